// Round 7
// baseline (446.425 us; speedup 1.0000x reference)
//
#include <hip/hip_runtime.h>
#include <cstdint>
#include <cstddef>

#define IN_CH 256
#define OUT_CH 128
#define NEG_SLOPE 0.2f
#define EPS 1e-16f

#define NXCD 8
// s_getreg hwreg(HW_REG_XCC_ID=20, offset=0, size=4) -> 20 | (0<<6) | (3<<11)
#define XCC_ID_HWREG 6164

typedef __attribute__((ext_vector_type(8))) short bf16x8;
typedef __attribute__((ext_vector_type(4))) float f32x4;

__device__ __forceinline__ unsigned short f2bf(float f) {
    unsigned int u = __float_as_uint(f);
    return (unsigned short)((u + 0x7fffu + ((u >> 16) & 1u)) >> 16);
}

// ---------------- one-time: w [256][128] f32 -> wt [128][256] bf16 (transposed) ----------------
__global__ __launch_bounds__(256) void convert_w_kernel(const float* __restrict__ w,
                                                        unsigned short* __restrict__ wt)
{
    const int n = blockIdx.x;     // 0..127  (output row = column of w)
    const int k = threadIdx.x;    // 0..255
    wt[(size_t)n * IN_CH + k] = f2bf(w[(size_t)k * OUT_CH + n]);
}

// ---------------- x f32 -> bf16, pure streaming ----------------
__global__ __launch_bounds__(256) void convert_x_kernel(
    const float* __restrict__ x, unsigned short* __restrict__ xb, long long nquad)
{
    const long long stride = (long long)gridDim.x * blockDim.x;
    for (long long i = (long long)blockIdx.x * blockDim.x + threadIdx.x;
         i < nquad; i += stride) {
        float4 v = ((const float4*)x)[i];
        ushort4 o;
        o.x = f2bf(v.x); o.y = f2bf(v.y); o.z = f2bf(v.z); o.w = f2bf(v.w);
        ((ushort4*)xb)[i] = o;
    }
}

// ---------------- MFMA GEMM: 64 rows x 128 cols per block, bf16 A direct ----------------
// A-frag: A[m=lane&15][k=quad*8+j]  one bf16x8 load from xb
// B-frag: B[k=quad*8+j][n=lane&15]  direct from wt[n][k] (bf16, L2-hot)
// C/D:    D[row=quad*4+r][col=lane&15]   (verified layout, m89/m91)
__global__ __launch_bounds__(256) void gemm_kernel(
    const unsigned short* __restrict__ xb, const unsigned short* __restrict__ wt,
    const float* __restrict__ att_s, const float* __restrict__ att_d,
    unsigned short* __restrict__ xpb, float* __restrict__ asrc, float* __restrict__ adst,
    int M)
{
    const int bid  = blockIdx.x;
    const int tid  = threadIdx.x;
    const int wv   = tid >> 6;
    const int lane = tid & 63;
    const int lm   = lane & 15;
    const int quad = lane >> 4;
    const int arow = bid * 64 + wv * 16 + lm;
    const bool av  = arow < M;
    const unsigned short* xrow = xb + (size_t)arow * IN_CH + quad * 8;

    f32x4 acc[8];
#pragma unroll
    for (int t = 0; t < 8; ++t) acc[t] = (f32x4){0.f, 0.f, 0.f, 0.f};

#pragma unroll
    for (int kk = 0; kk < 8; ++kk) {
        const int k0 = kk * 32;
        bf16x8 af = {0, 0, 0, 0, 0, 0, 0, 0};
        if (av) af = *(const bf16x8*)(xrow + k0);
#pragma unroll
        for (int t = 0; t < 8; ++t) {
            bf16x8 bf = *(const bf16x8*)(wt + (size_t)(16 * t + lm) * IN_CH + k0 + quad * 8);
            acc[t] = __builtin_amdgcn_mfma_f32_16x16x32_bf16(af, bf, acc[t], 0, 0, 0);
        }
    }

    // epilogue: write bf16 xp + per-row att dots (reduced over the 16 lm lanes)
    float asw[8], adw[8];
#pragma unroll
    for (int t = 0; t < 8; ++t) {
        asw[t] = att_s[16 * t + lm];
        adw[t] = att_d[16 * t + lm];
    }
#pragma unroll
    for (int r = 0; r < 4; ++r) {
        const int orow = bid * 64 + wv * 16 + quad * 4 + r;
        if (orow < M) {   // uniform across lm group
            float ps = 0.f, pd = 0.f;
            unsigned short* xr = xpb + (size_t)orow * OUT_CH + lm;
#pragma unroll
            for (int t = 0; t < 8; ++t) {
                float v = acc[t][r];
                xr[16 * t] = f2bf(v);
                ps += v * asw[t];
                pd += v * adw[t];
            }
#pragma unroll
            for (int m = 1; m < 16; m <<= 1) {
                ps += __shfl_xor(ps, m, 16);
                pd += __shfl_xor(pd, m, 16);
            }
            if (lm == 0) { asrc[orow] = ps; adst[orow] = pd; }
        }
    }
}

// ---------------- hist: XCD-local replicas + workgroup-scope atomics ----------------
// RETEST in the right regime (rounds 1-2 nulls were gemm-masked). Replica
// chosen by physical XCC_ID; workgroup scope keeps the RMW in the local TCC.
// pw[e] = (xcd<<27) | pos.
__global__ __launch_bounds__(256) void hist_kernel(
    const int* __restrict__ src, const int* __restrict__ dst,
    int* __restrict__ deg_part, int N, int* __restrict__ pw, int E, int nblk)
{
    const int xcd = (int)(__builtin_amdgcn_s_getreg(XCC_ID_HWREG) & 7u);
    int* mydeg = deg_part + (size_t)xcd * N;
    const int T = nblk * 256;
    const int e0 = blockIdx.x * 256 + threadIdx.x;
#pragma unroll
    for (int k = 0; k < 4; ++k) {
        const int e = e0 + k * T;
        if (e < E) {
            int s = src[e], d = dst[e];
            if (s != d) {
                int pos = __hip_atomic_fetch_add(&mydeg[d], 1,
                                                 __ATOMIC_RELAXED,
                                                 __HIP_MEMORY_SCOPE_WORKGROUP);
                pw[e] = (xcd << 27) | pos;
            }
        }
    }
}

// ---- two-level scan over the 8 replicas: 256 blocks x 256 threads ----
#define SCAN_NB 256
#define SCAN_NT 256

__global__ __launch_bounds__(SCAN_NT) void scan_partial_kernel(
    const int* __restrict__ deg_part, int* __restrict__ bsum, int N)
{
    __shared__ int sh[SCAN_NT];
    const int chunk = (N + SCAN_NB - 1) / SCAN_NB;
    const int sub   = (chunk + SCAN_NT - 1) / SCAN_NT;
    const int b0 = blockIdx.x * chunk;
    const int t0 = b0 + threadIdx.x * sub;
    const int t1 = min(min(b0 + chunk, t0 + sub), N);
    int s = 0;
    for (int i = t0; i < t1; ++i) {
#pragma unroll
        for (int xx = 0; xx < NXCD; ++xx) s += deg_part[(size_t)xx * N + i];
    }
    sh[threadIdx.x] = s;
    __syncthreads();
    for (int off = SCAN_NT / 2; off > 0; off >>= 1) {
        if (threadIdx.x < off) sh[threadIdx.x] += sh[threadIdx.x + off];
        __syncthreads();
    }
    if (threadIdx.x == 0) bsum[blockIdx.x] = sh[0];
}

__global__ __launch_bounds__(SCAN_NB) void scan_blocksums_kernel(
    const int* __restrict__ bsum, int* __restrict__ boff,
    int* __restrict__ row_ptr, int N)
{
    __shared__ int sh[SCAN_NB];
    const int t = threadIdx.x;
    sh[t] = bsum[t];
    __syncthreads();
    for (int off = 1; off < SCAN_NB; off <<= 1) {
        int v = (t >= off) ? sh[t - off] : 0;
        __syncthreads();
        sh[t] += v;
        __syncthreads();
    }
    boff[t] = (t == 0) ? 0 : sh[t - 1];
    if (t == SCAN_NB - 1) row_ptr[N] = sh[t];
}

// fill: row_ptr[i] = global prefix; deg_part[x][i] rewritten in-place to the
// ABSOLUTE col[] base for (xcd=x, node=i)
__global__ __launch_bounds__(SCAN_NT) void scan_fill_kernel(
    int* __restrict__ deg_part, const int* __restrict__ boff,
    int* __restrict__ row_ptr, int N)
{
    __shared__ int sh[SCAN_NT];
    const int chunk = (N + SCAN_NB - 1) / SCAN_NB;
    const int sub   = (chunk + SCAN_NT - 1) / SCAN_NT;
    const int b0 = blockIdx.x * chunk;
    const int t0 = b0 + threadIdx.x * sub;
    const int t1 = min(min(b0 + chunk, t0 + sub), N);
    int s = 0;
    for (int i = t0; i < t1; ++i) {
#pragma unroll
        for (int xx = 0; xx < NXCD; ++xx) s += deg_part[(size_t)xx * N + i];
    }
    sh[threadIdx.x] = s;
    __syncthreads();
    for (int off = 1; off < SCAN_NT; off <<= 1) {
        int v = (threadIdx.x >= off) ? sh[threadIdx.x - off] : 0;
        __syncthreads();
        sh[threadIdx.x] += v;
        __syncthreads();
    }
    int run = boff[blockIdx.x] + ((threadIdx.x == 0) ? 0 : sh[threadIdx.x - 1]);
    for (int i = t0; i < t1; ++i) {
        row_ptr[i] = run;
#pragma unroll
        for (int xx = 0; xx < NXCD; ++xx) {
            int c = deg_part[(size_t)xx * N + i];
            deg_part[(size_t)xx * N + i] = run;
            run += c;
        }
    }
}

// scatter via absolute per-(xcd,node) bases. NEW: also precompute per-edge
// softmax numerator ex = exp(lrelu(asrc[s]+adst[d])) into exa[slot] so the
// aggregate loop reads it coalesced instead of gathering asrc + expf per edge.
__global__ __launch_bounds__(256) void scatter_kernel(
    const int* __restrict__ src, const int* __restrict__ dst,
    const int* __restrict__ deg_part, int N, const int* __restrict__ pw,
    const float* __restrict__ asrc, const float* __restrict__ adst,
    int* __restrict__ col, float* __restrict__ exa, int E, int nblk)
{
    const int T = nblk * 256;
    const int e0 = blockIdx.x * 256 + threadIdx.x;
#pragma unroll
    for (int k = 0; k < 8; ++k) {
        const int e = e0 + k * T;
        if (e < E) {
            int s = src[e], d = dst[e];
            if (s != d) {
                unsigned int p = (unsigned int)pw[e];
                int xcd = (int)(p >> 27);
                int pos = (int)(p & 0x07ffffffu);
                int slot = deg_part[(size_t)xcd * N + d] + pos;
                float lg = asrc[s] + adst[d];
                lg = (lg > 0.f) ? lg : lg * NEG_SLOPE;
                col[slot] = s;
                exa[slot] = __expf(lg);
            }
        }
    }
}

// ---------------- Aggregation: one wave per dst node, coalesced col+exa ----------------
__global__ __launch_bounds__(256) void aggregate_kernel(
    const unsigned short* __restrict__ xpb, const float* __restrict__ asrc,
    const float* __restrict__ adst, const int* __restrict__ row_ptr,
    const int* __restrict__ col, const float* __restrict__ exa,
    const float* __restrict__ bias, float* __restrict__ out, int N)
{
    const int n = (int)((blockIdx.x * blockDim.x + threadIdx.x) >> 6);
    const int lane = threadIdx.x & 63;
    if (n >= N) return;
    const unsigned int* xpw = (const unsigned int*)xpb;   // 64 uints (=2 bf16) per row

    float ax0 = 0.f, ay0 = 0.f, ax1 = 0.f, ay1 = 0.f;
    float ax2 = 0.f, ay2 = 0.f, ax3 = 0.f, ay3 = 0.f;
    float den = 0.f;

    { // self loop (ex computed inline; only once per node)
        float lg = asrc[n] + adst[n];
        lg = (lg > 0.f) ? lg : lg * NEG_SLOPE;
        float ex = __expf(lg);
        den += ex;
        unsigned int v = xpw[(size_t)n * 64 + lane];
        ax0 += ex * __uint_as_float(v << 16);
        ay0 += ex * __uint_as_float(v & 0xffff0000u);
    }

    const int beg = row_ptr[n], end = row_ptr[n + 1];
    for (int base = beg; base < end; base += 64) {
        const int idx = base + lane;
        int s = 0; float ex = 0.f;
        if (idx < end) {
            s  = col[idx];
            ex = exa[idx];
        }
        const int cnt = min(64, end - base);
        int j = 0;
        for (; j + 4 <= cnt; j += 4) {
            float e0 = __shfl(ex, j, 64),     e1 = __shfl(ex, j + 1, 64);
            float e2 = __shfl(ex, j + 2, 64), e3 = __shfl(ex, j + 3, 64);
            int   s0 = __shfl(s, j, 64),      s1 = __shfl(s, j + 1, 64);
            int   s2 = __shfl(s, j + 2, 64),  s3 = __shfl(s, j + 3, 64);
            unsigned int v0 = xpw[(size_t)s0 * 64 + lane];
            unsigned int v1 = xpw[(size_t)s1 * 64 + lane];
            unsigned int v2 = xpw[(size_t)s2 * 64 + lane];
            unsigned int v3 = xpw[(size_t)s3 * 64 + lane];
            den += (e0 + e1) + (e2 + e3);
            ax0 += e0 * __uint_as_float(v0 << 16);
            ay0 += e0 * __uint_as_float(v0 & 0xffff0000u);
            ax1 += e1 * __uint_as_float(v1 << 16);
            ay1 += e1 * __uint_as_float(v1 & 0xffff0000u);
            ax2 += e2 * __uint_as_float(v2 << 16);
            ay2 += e2 * __uint_as_float(v2 & 0xffff0000u);
            ax3 += e3 * __uint_as_float(v3 << 16);
            ay3 += e3 * __uint_as_float(v3 & 0xffff0000u);
        }
        for (; j < cnt; ++j) {
            float e0 = __shfl(ex, j, 64);
            int   s0 = __shfl(s, j, 64);
            unsigned int v0 = xpw[(size_t)s0 * 64 + lane];
            den += e0;
            ax0 += e0 * __uint_as_float(v0 << 16);
            ay0 += e0 * __uint_as_float(v0 & 0xffff0000u);
        }
    }

    const float inv = 1.f / (den + EPS);
    const float2 bv = ((const float2*)bias)[lane];
    float2 o;
    o.x = ((ax0 + ax1) + (ax2 + ax3)) * inv + bv.x;
    o.y = ((ay0 + ay1) + (ay2 + ay3)) * inv + bv.y;
    ((float2*)out)[(size_t)n * 64 + lane] = o;
}

// ---------------- launch ----------------
extern "C" void kernel_launch(void* const* d_in, const int* in_sizes, int n_in,
                              void* d_out, int out_size, void* d_ws, size_t ws_size,
                              hipStream_t stream)
{
    const float* x     = (const float*)d_in[0];
    const int*   ei    = (const int*)d_in[1];
    const float* w     = (const float*)d_in[2];
    const float* att_s = (const float*)d_in[3];
    const float* att_d = (const float*)d_in[4];
    const float* bias  = (const float*)d_in[5];
    float* out = (float*)d_out;

    const int N = in_sizes[0] / IN_CH;
    const int E = in_sizes[1] / 2;
    const int* src = ei;
    const int* dst = ei + E;

    char* p = (char*)d_ws;
    auto take = [&](size_t bytes) { char* q = p; p += (bytes + 255) & ~size_t(255); return q; };
    unsigned short* xpb = (unsigned short*)take((size_t)N * OUT_CH * 2);
    unsigned short* wt  = (unsigned short*)take((size_t)OUT_CH * IN_CH * 2);
    unsigned short* xb  = (unsigned short*)take((size_t)N * IN_CH * 2);   // bf16 x
    float* asrc   = (float*)take((size_t)N * 4);
    float* adst   = (float*)take((size_t)N * 4);
    int*   deg_part = (int*)take((size_t)NXCD * N * 4);   // per-XCD replicas
    int*   row_ptr  = (int*)take((size_t)(N + 1) * 4);
    int*   bsum   = (int*)take(SCAN_NB * 4);
    int*   boff   = (int*)take(SCAN_NB * 4);
    int*   pw     = (int*)take((size_t)E * 4);
    int*   col    = (int*)take((size_t)E * 4);
    float* exa    = (float*)take((size_t)E * 4);

    hipMemsetAsync(deg_part, 0, (size_t)NXCD * N * 4, stream);
    convert_w_kernel<<<OUT_CH, IN_CH, 0, stream>>>(w, wt);

    const long long nquad = (long long)N * IN_CH / 4;
    convert_x_kernel<<<2048, 256, 0, stream>>>(x, xb, nquad);

    const int hist_blocks = (E + 256 * 4 - 1) / (256 * 4);
    hist_kernel<<<hist_blocks, 256, 0, stream>>>(src, dst, deg_part, N, pw, E, hist_blocks);

    const int gemm_blocks = (N + 63) / 64;
    gemm_kernel<<<gemm_blocks, 256, 0, stream>>>(xb, wt, att_s, att_d, xpb, asrc, adst, N);

    scan_partial_kernel<<<SCAN_NB, SCAN_NT, 0, stream>>>(deg_part, bsum, N);
    scan_blocksums_kernel<<<1, SCAN_NB, 0, stream>>>(bsum, boff, row_ptr, N);
    scan_fill_kernel<<<SCAN_NB, SCAN_NT, 0, stream>>>(deg_part, boff, row_ptr, N);

    const int sc_blocks = (E + 256 * 8 - 1) / (256 * 8);
    scatter_kernel<<<sc_blocks, 256, 0, stream>>>(src, dst, deg_part, N, pw,
                                                  asrc, adst, col, exa, E, sc_blocks);

    aggregate_kernel<<<(N + 3) / 4, 256, 0, stream>>>(
        xpb, asrc, adst, row_ptr, col, exa, bias, out, N);
}

// Round 8
// 384.024 us; speedup vs baseline: 1.1625x; 1.1625x over previous
//
#include <hip/hip_runtime.h>
#include <cstdint>
#include <cstddef>

#define IN_CH 256
#define OUT_CH 128
#define NEG_SLOPE 0.2f
#define EPS 1e-16f

typedef __attribute__((ext_vector_type(8))) short bf16x8;
typedef __attribute__((ext_vector_type(4))) float f32x4;

__device__ __forceinline__ unsigned short f2bf(float f) {
    unsigned int u = __float_as_uint(f);
    return (unsigned short)((u + 0x7fffu + ((u >> 16) & 1u)) >> 16);
}

// ================= K1: fused hist | convert_x | convert_w (independent) =================
__device__ __forceinline__ void hist_body(
    int bid, int nblk, const int* __restrict__ src, const int* __restrict__ dst,
    int* __restrict__ deg, int* __restrict__ pw, int E)
{
    const int T = nblk * 256;
    const int e0 = bid * 256 + threadIdx.x;
#pragma unroll
    for (int k = 0; k < 8; ++k) {
        const int e = e0 + k * T;
        if (e < E) {
            int s = src[e], d = dst[e];
            if (s != d) pw[e] = atomicAdd(&deg[d], 1);
        }
    }
}

__device__ __forceinline__ void convert_x_body(
    int bid, int nblk, const float* __restrict__ x, unsigned short* __restrict__ xb,
    long long nquad)
{
    const long long stride = (long long)nblk * 256;
    for (long long i = (long long)bid * 256 + threadIdx.x; i < nquad; i += stride) {
        float4 v = ((const float4*)x)[i];
        ushort4 o;
        o.x = f2bf(v.x); o.y = f2bf(v.y); o.z = f2bf(v.z); o.w = f2bf(v.w);
        ((ushort4*)xb)[i] = o;
    }
}

__global__ __launch_bounds__(256) void fused_pre_kernel(
    const int* __restrict__ src, const int* __restrict__ dst,
    int* __restrict__ deg, int* __restrict__ pw, int E, int hist_blocks,
    const float* __restrict__ x, unsigned short* __restrict__ xb, long long nquad,
    int cx_blocks,
    const float* __restrict__ w, unsigned short* __restrict__ wt)
{
    const int b = blockIdx.x;
    if (b < hist_blocks) {
        hist_body(b, hist_blocks, src, dst, deg, pw, E);
    } else if (b < hist_blocks + cx_blocks) {
        convert_x_body(b - hist_blocks, cx_blocks, x, xb, nquad);
    } else {
        const int n = b - hist_blocks - cx_blocks;   // 0..127
        const int k = threadIdx.x;                   // 0..255
        wt[(size_t)n * IN_CH + k] = f2bf(w[(size_t)k * OUT_CH + n]);
    }
}

// ================= K2: fused scan_partial | gemm =================
#define SCAN_NB 256
#define SCAN_NT 256

__device__ __forceinline__ void scan_partial_body(
    int bid, const int* __restrict__ deg, int* __restrict__ bsum, int N)
{
    __shared__ int sh[SCAN_NT];
    const int chunk = (N + SCAN_NB - 1) / SCAN_NB;
    const int sub   = (chunk + SCAN_NT - 1) / SCAN_NT;
    const int b0 = bid * chunk;
    const int t0 = b0 + threadIdx.x * sub;
    const int t1 = min(min(b0 + chunk, t0 + sub), N);
    int s = 0;
    for (int i = t0; i < t1; ++i) s += deg[i];
    sh[threadIdx.x] = s;
    __syncthreads();
    for (int off = SCAN_NT / 2; off > 0; off >>= 1) {
        if (threadIdx.x < off) sh[threadIdx.x] += sh[threadIdx.x + off];
        __syncthreads();
    }
    if (threadIdx.x == 0) bsum[bid] = sh[0];
}

// MFMA GEMM body: 64 rows x 128 cols per block, bf16 A direct from xb.
// A-frag: A[m=lane&15][k=quad*8+j]  one bf16x8 load
// B-frag: B[k=quad*8+j][n=lane&15]  from wt[n][k] (bf16, L2-hot)
// C/D:    D[row=quad*4+r][col=lane&15]   (verified layout, m89/m91)
__device__ __forceinline__ void gemm_body(
    int bid, const unsigned short* __restrict__ xb, const unsigned short* __restrict__ wt,
    const float* __restrict__ att_s, const float* __restrict__ att_d,
    unsigned short* __restrict__ xpb, float* __restrict__ asrc, float* __restrict__ adst,
    int M)
{
    const int tid  = threadIdx.x;
    const int wv   = tid >> 6;
    const int lane = tid & 63;
    const int lm   = lane & 15;
    const int quad = lane >> 4;
    const int arow = bid * 64 + wv * 16 + lm;
    const bool av  = arow < M;
    const unsigned short* xrow = xb + (size_t)arow * IN_CH + quad * 8;

    f32x4 acc[8];
#pragma unroll
    for (int t = 0; t < 8; ++t) acc[t] = (f32x4){0.f, 0.f, 0.f, 0.f};

#pragma unroll
    for (int kk = 0; kk < 8; ++kk) {
        const int k0 = kk * 32;
        bf16x8 af = {0, 0, 0, 0, 0, 0, 0, 0};
        if (av) af = *(const bf16x8*)(xrow + k0);
#pragma unroll
        for (int t = 0; t < 8; ++t) {
            bf16x8 bf = *(const bf16x8*)(wt + (size_t)(16 * t + lm) * IN_CH + k0 + quad * 8);
            acc[t] = __builtin_amdgcn_mfma_f32_16x16x32_bf16(af, bf, acc[t], 0, 0, 0);
        }
    }

    float asw[8], adw[8];
#pragma unroll
    for (int t = 0; t < 8; ++t) {
        asw[t] = att_s[16 * t + lm];
        adw[t] = att_d[16 * t + lm];
    }
#pragma unroll
    for (int r = 0; r < 4; ++r) {
        const int orow = bid * 64 + wv * 16 + quad * 4 + r;
        if (orow < M) {   // uniform across lm group
            float ps = 0.f, pd = 0.f;
            unsigned short* xr = xpb + (size_t)orow * OUT_CH + lm;
#pragma unroll
            for (int t = 0; t < 8; ++t) {
                float v = acc[t][r];
                xr[16 * t] = f2bf(v);
                ps += v * asw[t];
                pd += v * adw[t];
            }
#pragma unroll
            for (int m = 1; m < 16; m <<= 1) {
                ps += __shfl_xor(ps, m, 16);
                pd += __shfl_xor(pd, m, 16);
            }
            if (lm == 0) { asrc[orow] = ps; adst[orow] = pd; }
        }
    }
}

__global__ __launch_bounds__(256) void fused_gemm_scan_kernel(
    const unsigned short* __restrict__ xb, const unsigned short* __restrict__ wt,
    const float* __restrict__ att_s, const float* __restrict__ att_d,
    unsigned short* __restrict__ xpb, float* __restrict__ asrc, float* __restrict__ adst,
    int M, const int* __restrict__ deg, int* __restrict__ bsum)
{
    if ((int)blockIdx.x < SCAN_NB)
        scan_partial_body(blockIdx.x, deg, bsum, M);
    else
        gemm_body(blockIdx.x - SCAN_NB, xb, wt, att_s, att_d, xpb, asrc, adst, M);
}

// ================= scans =================
__global__ __launch_bounds__(SCAN_NB) void scan_blocksums_kernel(
    const int* __restrict__ bsum, int* __restrict__ boff,
    int* __restrict__ row_ptr, int N)
{
    __shared__ int sh[SCAN_NB];
    const int t = threadIdx.x;
    sh[t] = bsum[t];
    __syncthreads();
    for (int off = 1; off < SCAN_NB; off <<= 1) {
        int v = (t >= off) ? sh[t - off] : 0;
        __syncthreads();
        sh[t] += v;
        __syncthreads();
    }
    boff[t] = (t == 0) ? 0 : sh[t - 1];
    if (t == SCAN_NB - 1) row_ptr[N] = sh[t];
}

__global__ __launch_bounds__(SCAN_NT) void scan_fill_kernel(
    const int* __restrict__ deg, const int* __restrict__ boff,
    int* __restrict__ row_ptr, int N)
{
    __shared__ int sh[SCAN_NT];
    const int chunk = (N + SCAN_NB - 1) / SCAN_NB;
    const int sub   = (chunk + SCAN_NT - 1) / SCAN_NT;
    const int b0 = blockIdx.x * chunk;
    const int t0 = b0 + threadIdx.x * sub;
    const int t1 = min(min(b0 + chunk, t0 + sub), N);
    int s = 0;
    for (int i = t0; i < t1; ++i) s += deg[i];
    sh[threadIdx.x] = s;
    __syncthreads();
    for (int off = 1; off < SCAN_NT; off <<= 1) {
        int v = (threadIdx.x >= off) ? sh[threadIdx.x - off] : 0;
        __syncthreads();
        sh[threadIdx.x] += v;
        __syncthreads();
    }
    int run = boff[blockIdx.x] + ((threadIdx.x == 0) ? 0 : sh[threadIdx.x - 1]);
    for (int i = t0; i < t1; ++i) {
        row_ptr[i] = run;
        run += deg[i];
    }
}

// ================= scatter: atomic-free, col only =================
__global__ __launch_bounds__(256) void scatter_kernel(
    const int* __restrict__ src, const int* __restrict__ dst,
    const int* __restrict__ row_ptr, const int* __restrict__ pw,
    int* __restrict__ col, int E, int nblk)
{
    const int T = nblk * 256;
    const int e0 = blockIdx.x * 256 + threadIdx.x;
#pragma unroll
    for (int k = 0; k < 8; ++k) {
        const int e = e0 + k * T;
        if (e < E) {
            int s = src[e], d = dst[e];
            if (s != d) col[row_ptr[d] + pw[e]] = s;
        }
    }
}

// ================= aggregate: one wave per dst node, batch-8 gathers =================
__global__ __launch_bounds__(256) void aggregate_kernel(
    const unsigned short* __restrict__ xpb, const float* __restrict__ asrc,
    const float* __restrict__ adst, const int* __restrict__ row_ptr,
    const int* __restrict__ col, const float* __restrict__ bias,
    float* __restrict__ out, int N)
{
    const int n = (int)((blockIdx.x * blockDim.x + threadIdx.x) >> 6);
    const int lane = threadIdx.x & 63;
    if (n >= N) return;
    const float a_d = adst[n];
    const unsigned int* xpw = (const unsigned int*)xpb;   // 64 uints (=2 bf16) per row

    float ax0 = 0.f, ay0 = 0.f, ax1 = 0.f, ay1 = 0.f;
    float ax2 = 0.f, ay2 = 0.f, ax3 = 0.f, ay3 = 0.f;
    float den = 0.f;

    { // self loop
        float lg = asrc[n] + a_d;
        lg = (lg > 0.f) ? lg : lg * NEG_SLOPE;
        float ex = __expf(lg);
        den += ex;
        unsigned int v = xpw[(size_t)n * 64 + lane];
        ax0 += ex * __uint_as_float(v << 16);
        ay0 += ex * __uint_as_float(v & 0xffff0000u);
    }

    const int beg = row_ptr[n], end = row_ptr[n + 1];
    for (int base = beg; base < end; base += 64) {
        const int idx = base + lane;
        int s = 0; float ex = 0.f;
        if (idx < end) {
            s = col[idx];
            float lg = asrc[s] + a_d;
            lg = (lg > 0.f) ? lg : lg * NEG_SLOPE;
            ex = __expf(lg);
        }
        const int cnt = min(64, end - base);
        int j = 0;
        for (; j + 8 <= cnt; j += 8) {   // batch-8: 8 gathers in flight
            float e0 = __shfl(ex, j, 64),     e1 = __shfl(ex, j + 1, 64);
            float e2 = __shfl(ex, j + 2, 64), e3 = __shfl(ex, j + 3, 64);
            float e4 = __shfl(ex, j + 4, 64), e5 = __shfl(ex, j + 5, 64);
            float e6 = __shfl(ex, j + 6, 64), e7 = __shfl(ex, j + 7, 64);
            int   s0 = __shfl(s, j, 64),      s1 = __shfl(s, j + 1, 64);
            int   s2 = __shfl(s, j + 2, 64),  s3 = __shfl(s, j + 3, 64);
            int   s4 = __shfl(s, j + 4, 64),  s5 = __shfl(s, j + 5, 64);
            int   s6 = __shfl(s, j + 6, 64),  s7 = __shfl(s, j + 7, 64);
            unsigned int v0 = xpw[(size_t)s0 * 64 + lane];
            unsigned int v1 = xpw[(size_t)s1 * 64 + lane];
            unsigned int v2 = xpw[(size_t)s2 * 64 + lane];
            unsigned int v3 = xpw[(size_t)s3 * 64 + lane];
            unsigned int v4 = xpw[(size_t)s4 * 64 + lane];
            unsigned int v5 = xpw[(size_t)s5 * 64 + lane];
            unsigned int v6 = xpw[(size_t)s6 * 64 + lane];
            unsigned int v7 = xpw[(size_t)s7 * 64 + lane];
            den += ((e0 + e1) + (e2 + e3)) + ((e4 + e5) + (e6 + e7));
            ax0 += e0 * __uint_as_float(v0 << 16);
            ay0 += e0 * __uint_as_float(v0 & 0xffff0000u);
            ax1 += e1 * __uint_as_float(v1 << 16);
            ay1 += e1 * __uint_as_float(v1 & 0xffff0000u);
            ax2 += e2 * __uint_as_float(v2 << 16);
            ay2 += e2 * __uint_as_float(v2 & 0xffff0000u);
            ax3 += e3 * __uint_as_float(v3 << 16);
            ay3 += e3 * __uint_as_float(v3 & 0xffff0000u);
            ax0 += e4 * __uint_as_float(v4 << 16);
            ay0 += e4 * __uint_as_float(v4 & 0xffff0000u);
            ax1 += e5 * __uint_as_float(v5 << 16);
            ay1 += e5 * __uint_as_float(v5 & 0xffff0000u);
            ax2 += e6 * __uint_as_float(v6 << 16);
            ay2 += e6 * __uint_as_float(v6 & 0xffff0000u);
            ax3 += e7 * __uint_as_float(v7 << 16);
            ay3 += e7 * __uint_as_float(v7 & 0xffff0000u);
        }
        for (; j + 4 <= cnt; j += 4) {
            float e0 = __shfl(ex, j, 64),     e1 = __shfl(ex, j + 1, 64);
            float e2 = __shfl(ex, j + 2, 64), e3 = __shfl(ex, j + 3, 64);
            int   s0 = __shfl(s, j, 64),      s1 = __shfl(s, j + 1, 64);
            int   s2 = __shfl(s, j + 2, 64),  s3 = __shfl(s, j + 3, 64);
            unsigned int v0 = xpw[(size_t)s0 * 64 + lane];
            unsigned int v1 = xpw[(size_t)s1 * 64 + lane];
            unsigned int v2 = xpw[(size_t)s2 * 64 + lane];
            unsigned int v3 = xpw[(size_t)s3 * 64 + lane];
            den += (e0 + e1) + (e2 + e3);
            ax0 += e0 * __uint_as_float(v0 << 16);
            ay0 += e0 * __uint_as_float(v0 & 0xffff0000u);
            ax1 += e1 * __uint_as_float(v1 << 16);
            ay1 += e1 * __uint_as_float(v1 & 0xffff0000u);
            ax2 += e2 * __uint_as_float(v2 << 16);
            ay2 += e2 * __uint_as_float(v2 & 0xffff0000u);
            ax3 += e3 * __uint_as_float(v3 << 16);
            ay3 += e3 * __uint_as_float(v3 & 0xffff0000u);
        }
        for (; j < cnt; ++j) {
            float e0 = __shfl(ex, j, 64);
            int   s0 = __shfl(s, j, 64);
            unsigned int v0 = xpw[(size_t)s0 * 64 + lane];
            den += e0;
            ax0 += e0 * __uint_as_float(v0 << 16);
            ay0 += e0 * __uint_as_float(v0 & 0xffff0000u);
        }
    }

    const float inv = 1.f / (den + EPS);
    const float2 bv = ((const float2*)bias)[lane];
    float2 o;
    o.x = ((ax0 + ax1) + (ax2 + ax3)) * inv + bv.x;
    o.y = ((ay0 + ay1) + (ay2 + ay3)) * inv + bv.y;
    ((float2*)out)[(size_t)n * 64 + lane] = o;
}

// ---------------- launch ----------------
extern "C" void kernel_launch(void* const* d_in, const int* in_sizes, int n_in,
                              void* d_out, int out_size, void* d_ws, size_t ws_size,
                              hipStream_t stream)
{
    const float* x     = (const float*)d_in[0];
    const int*   ei    = (const int*)d_in[1];
    const float* w     = (const float*)d_in[2];
    const float* att_s = (const float*)d_in[3];
    const float* att_d = (const float*)d_in[4];
    const float* bias  = (const float*)d_in[5];
    float* out = (float*)d_out;

    const int N = in_sizes[0] / IN_CH;
    const int E = in_sizes[1] / 2;
    const int* src = ei;
    const int* dst = ei + E;

    char* p = (char*)d_ws;
    auto take = [&](size_t bytes) { char* q = p; p += (bytes + 255) & ~size_t(255); return q; };
    unsigned short* xpb = (unsigned short*)take((size_t)N * OUT_CH * 2);
    unsigned short* wt  = (unsigned short*)take((size_t)OUT_CH * IN_CH * 2);
    unsigned short* xb  = (unsigned short*)take((size_t)N * IN_CH * 2);   // bf16 x
    float* asrc   = (float*)take((size_t)N * 4);
    float* adst   = (float*)take((size_t)N * 4);
    int*   deg    = (int*)take((size_t)N * 4);
    int*   row_ptr= (int*)take((size_t)(N + 1) * 4);
    int*   bsum   = (int*)take(SCAN_NB * 4);
    int*   boff   = (int*)take(SCAN_NB * 4);
    int*   pw     = (int*)take((size_t)E * 4);
    int*   col    = (int*)take((size_t)E * 4);

    hipMemsetAsync(deg, 0, (size_t)N * 4, stream);

    // K1: hist | convert_x | convert_w  (independent; hist is the long pole)
    const int hist_blocks = (E + 256 * 8 - 1) / (256 * 8);
    const int cx_blocks = 1024;
    const long long nquad = (long long)N * IN_CH / 4;
    fused_pre_kernel<<<hist_blocks + cx_blocks + OUT_CH, 256, 0, stream>>>(
        src, dst, deg, pw, E, hist_blocks,
        x, xb, nquad, cx_blocks, w, wt);

    // K2: scan_partial | gemm
    const int gemm_blocks = (N + 63) / 64;
    fused_gemm_scan_kernel<<<SCAN_NB + gemm_blocks, 256, 0, stream>>>(
        xb, wt, att_s, att_d, xpb, asrc, adst, N, deg, bsum);

    scan_blocksums_kernel<<<1, SCAN_NB, 0, stream>>>(bsum, boff, row_ptr, N);
    scan_fill_kernel<<<SCAN_NB, SCAN_NT, 0, stream>>>(deg, boff, row_ptr, N);

    const int sc_blocks = (E + 256 * 8 - 1) / (256 * 8);
    scatter_kernel<<<sc_blocks, 256, 0, stream>>>(src, dst, row_ptr, pw, col, E, sc_blocks);

    aggregate_kernel<<<(N + 3) / 4, 256, 0, stream>>>(
        xpb, asrc, adst, row_ptr, col, bias, out, N);
}